// Round 7
// baseline (598.199 us; speedup 1.0000x reference)
//
#include <hip/hip_runtime.h>
#include <math.h>

#define N_NODES 50000
#define N_EDGES 800000
#define HEADS 4
#define HID 64
#define FDIM 256      // HEADS*HID == F_IN == 256 for both layers
#define LDA 40        // padded LDS k-stride (halves): 80B row stride
#define SCAN_CHUNK 1024
#define SCAN_NB ((N_NODES + SCAN_CHUNK - 1) / SCAN_CHUNK)   // 49
#define SLAB ((size_t)N_NODES * 32)   // halves per 32-feature slice slab

typedef __attribute__((ext_vector_type(8))) _Float16 half8;
typedef __attribute__((ext_vector_type(4))) _Float16 half4;
typedef __attribute__((ext_vector_type(4))) float f32x4;

// ---------------------------------------------------------------- CSR build

__global__ __launch_bounds__(256) void hist_kernel(const int* __restrict__ dst,
                                                   int* __restrict__ counts, int E) {
    int i = blockIdx.x * blockDim.x + threadIdx.x;
    if (i < E) atomicAdd(&counts[dst[i]], 1);
}

__global__ __launch_bounds__(256) void scan_local(const int* __restrict__ counts,
                                                  int* __restrict__ offs,
                                                  int* __restrict__ bsum, int n) {
    __shared__ int part[256];
    const int b = blockIdx.x, t = threadIdx.x;
    const int base = b * SCAN_CHUNK + t * 4;
    int v[4];
#pragma unroll
    for (int j = 0; j < 4; j++) {
        int idx = base + j;
        v[j] = (idx < n) ? counts[idx] : 0;
    }
    int s0 = v[0], s1 = s0 + v[1], s2 = s1 + v[2], s3 = s2 + v[3];
    part[t] = s3;
    __syncthreads();
    for (int off = 1; off < 256; off <<= 1) {
        int x = (t >= off) ? part[t - off] : 0;
        __syncthreads();
        part[t] += x;
        __syncthreads();
    }
    int prefix = (t > 0) ? part[t - 1] : 0;
    int e[4] = {prefix, prefix + s0, prefix + s1, prefix + s2};
#pragma unroll
    for (int j = 0; j < 4; j++) {
        int idx = base + j;
        if (idx < n) offs[idx] = e[j];
    }
    if (t == 255) bsum[b] = part[255];
}

__global__ __launch_bounds__(64) void scan_bsum(int* __restrict__ bsum,
                                                int* __restrict__ offs, int nb, int n) {
    int lane = threadIdx.x;
    int own = (lane < nb) ? bsum[lane] : 0;
    int v = own;
    for (int off = 1; off < 64; off <<= 1) {
        int x = __shfl_up(v, off);
        if (lane >= off) v += x;
    }
    if (lane < nb) bsum[lane] = v - own;   // exclusive prefix
    if (lane == nb - 1) offs[n] = v;       // grand total
}

__global__ __launch_bounds__(256) void scan_add(int* __restrict__ offs,
                                                const int* __restrict__ bsum, int n) {
    const int b = blockIdx.x;
    const int p = bsum[b];
    const int base = b * SCAN_CHUNK + threadIdx.x * 4;
#pragma unroll
    for (int j = 0; j < 4; j++) {
        int idx = base + j;
        if (idx < n) offs[idx] += p;
    }
}

__global__ __launch_bounds__(256) void scatter_kernel(const int* __restrict__ src,
                                                      const int* __restrict__ dst,
                                                      const int* __restrict__ offs,
                                                      int* __restrict__ cursor,
                                                      int* __restrict__ csr_src, int E) {
    int i = blockIdx.x * blockDim.x + threadIdx.x;
    if (i < E) {
        int d = dst[i];
        int p = offs[d] + atomicAdd(&cursor[d], 1);
        csr_src[p] = src[i];
    }
}

// -------------------------------------------- prep: W transpose-cast

__global__ __launch_bounds__(256) void wcast_kernel(const float* __restrict__ W0,
                                                    const float* __restrict__ W1,
                                                    _Float16* __restrict__ wt0,
                                                    _Float16* __restrict__ wt1) {
    const float* W = blockIdx.y ? W1 : W0;
    _Float16* wt = blockIdx.y ? wt1 : wt0;
    int n = blockIdx.x * 16 + (threadIdx.x >> 4);
    int k0 = (threadIdx.x & 15) * 16;
    for (int j = 0; j < 16; j++)
        wt[n * FDIM + k0 + j] = (_Float16)W[(k0 + j) * FDIM + n];
}

// -------------------------------------------- fp16 MFMA GEMM + fused el/er
// C = A @ W (W pre-cast/transposed: Bt[n][k]).
// AMODE 0: A fp32 row-major (layer-1 input x), converted during staging.
// AMODE 1: A fp16 slice-major [slice][node][32] (h1 from layer-1 aggregate).
// feat16 written fp16 SLICE-MAJOR; el/er fused in epilogue (wave's 64-col
// quadrant == one head; width-16 shuffle completes the reduction).
template <int AMODE>
__global__ __launch_bounds__(256) void mfma_gemm(const float* __restrict__ A32,
                                                 const _Float16* __restrict__ A16,
                                                 const _Float16* __restrict__ Bt,
                                                 const float* __restrict__ al,
                                                 const float* __restrict__ ar,
                                                 _Float16* __restrict__ feat16,
                                                 float* __restrict__ el,
                                                 float* __restrict__ er) {
    __shared__ _Float16 ash[128][LDA];
    __shared__ _Float16 bsh[128][LDA];

    const int t = threadIdx.x;
    const int m0 = blockIdx.x * 128;
    const int n0 = blockIdx.y * 128;
    const int wave = t >> 6, lane = t & 63;
    const int quad = lane >> 4, l16 = lane & 15;
    const int wr = (wave >> 1) * 64;
    const int wc = (wave & 1) * 64;

    const f32x4 zero = {0.f, 0.f, 0.f, 0.f};
    f32x4 acc[4][4];
#pragma unroll
    for (int i = 0; i < 4; i++)
#pragma unroll
        for (int j = 0; j < 4; j++) acc[i][j] = zero;

    for (int kk = 0; kk < FDIM; kk += 32) {
        if constexpr (AMODE == 0) {
            // fp32 rows: 32 rows/pass x 4 passes; (t>>3) row, (t&7)*4 col
            const int ar_ = t >> 3, ac = (t & 7) * 4;
#pragma unroll
            for (int rr = 0; rr < 4; rr++) {
                int row = ar_ + rr * 32;
                int gr = m0 + row; if (gr >= N_NODES) gr = N_NODES - 1;
                float4 v = *(const float4*)&A32[(size_t)gr * FDIM + kk + ac];
                half4 h = {(_Float16)v.x, (_Float16)v.y, (_Float16)v.z, (_Float16)v.w};
                *(half4*)&ash[row][ac] = h;
            }
        } else {
            const int s0 = kk >> 5;   // this k-chunk == one slice
#pragma unroll
            for (int ii = 0; ii < 2; ii++) {
                int idx = t + ii * 256;
                int row = idx >> 2;
                int kb = (idx & 3) * 8;
                int gr = m0 + row; if (gr >= N_NODES) gr = N_NODES - 1;
                *(half8*)&ash[row][kb] = *(const half8*)&A16[(size_t)s0 * SLAB + (size_t)gr * 32 + kb];
            }
        }
#pragma unroll
        for (int ii = 0; ii < 2; ii++) {
            int idx = t + ii * 256;
            int row = idx >> 2;
            int kb = (idx & 3) * 8;
            *(half8*)&bsh[row][kb] = *(const half8*)&Bt[(size_t)(n0 + row) * FDIM + kk + kb];
        }
        __syncthreads();

        half8 af[4], bf[4];
#pragma unroll
        for (int i = 0; i < 4; i++) {
            af[i] = *(half8*)&ash[wr + i * 16 + l16][quad * 8];
            bf[i] = *(half8*)&bsh[wc + i * 16 + l16][quad * 8];
        }
#pragma unroll
        for (int mt = 0; mt < 4; mt++)
#pragma unroll
            for (int nt = 0; nt < 4; nt++)
                acc[mt][nt] = __builtin_amdgcn_mfma_f32_16x16x32_f16(af[mt], bf[nt], acc[mt][nt], 0, 0, 0);
        __syncthreads();
    }

    // ---- epilogue: slice-major feat16 store + fused el/er (wave's head = h)
    const int h = (n0 + wc) >> 6;
    float alv[4], arv[4];
#pragma unroll
    for (int nt = 0; nt < 4; nt++) {
        alv[nt] = al[n0 + wc + nt * 16 + l16];
        arv[nt] = ar[n0 + wc + nt * 16 + l16];
    }
#pragma unroll
    for (int mt = 0; mt < 4; mt++) {
        int m = m0 + wr + mt * 16 + quad * 4;
        float pl[4] = {0.f, 0.f, 0.f, 0.f}, pr[4] = {0.f, 0.f, 0.f, 0.f};
#pragma unroll
        for (int nt = 0; nt < 4; nt++) {
            int n = n0 + wc + nt * 16 + l16;
            int sl = n >> 5, within = n & 31;
#pragma unroll
            for (int r = 0; r < 4; r++) {
                float v = acc[mt][nt][r];
                if (m + r < N_NODES)
                    feat16[(size_t)sl * SLAB + (size_t)(m + r) * 32 + within] = (_Float16)v;
                pl[r] += v * alv[nt];
                pr[r] += v * arv[nt];
            }
        }
#pragma unroll
        for (int r = 0; r < 4; r++) {
            float a = pl[r], b = pr[r];
            for (int off = 8; off; off >>= 1) {
                a += __shfl_down(a, off, 16);
                b += __shfl_down(b, off, 16);
            }
            if (l16 == 0 && m + r < N_NODES) {
                el[(m + r) * 4 + h] = a;
                er[(m + r) * 4 + h] = b;
            }
        }
    }
}

// ------------------------------------------- fused softmax + aggregate (v3)
// Feature-slice x XCD partitioning: slice = blockIdx.x & 7 (round-robin
// dispatch heuristic -> one 3.2MB slice slab per XCD L2). 512-thread block,
// wave = (node, slice); 8 edge-slots x 8 lanes x half4 (32 feats/slice).
// Single-pass softmax (no max; logits O(1), ratio max-invariant); denominator
// completed by 3 shfl_xor steps across slots. No LDS, no barriers.
// mode 0: write h1 fp16 slice-major (layer-2 GEMM input, lives in d_out)
// mode 1: final fp32 head-major write
__global__ __launch_bounds__(512) void agg_fused(const _Float16* __restrict__ feat16,
                                                 const float* __restrict__ el,
                                                 const float* __restrict__ er,
                                                 const float* __restrict__ bias,
                                                 const int* __restrict__ offs,
                                                 const int* __restrict__ csr_src,
                                                 float* __restrict__ out,
                                                 _Float16* __restrict__ h1,
                                                 int mode) {
    const int wave = threadIdx.x >> 6;
    const int lane = threadIdx.x & 63;
    const int sl = blockIdx.x & 7;            // feature slice (== XCD, heuristic)
    const int n = (blockIdx.x >> 3) * 8 + wave;
    const int head = sl >> 1;
    const int half32 = (sl & 1) * 32;
    const int slot = lane >> 3;               // 8 edge slots
    const int fl = (lane & 7) * 4;            // feature offset within slice
    const int beg = offs[n];
    const int end = offs[n + 1];
    const float er_h = er[n * 4 + head];
    const _Float16* slab = feat16 + (size_t)sl * SLAB;

    float4 acc = make_float4(0.f, 0.f, 0.f, 0.f);
    float ssum = 0.f;
    for (int i = beg + slot; i < end; i += 8) {
        int s = csr_src[i];
        float e = el[s * 4 + head] + er_h;
        half4 v = *(const half4*)&slab[(size_t)s * 32 + fl];
        e = (e > 0.f) ? e : 0.2f * e;
        float w = __expf(e);
        ssum += w;
        acc.x += w * (float)v[0];
        acc.y += w * (float)v[1];
        acc.z += w * (float)v[2];
        acc.w += w * (float)v[3];
    }
    // reduce across the 8 slots (lane bits 3,4,5)
#pragma unroll
    for (int m = 8; m <= 32; m <<= 1) {
        acc.x += __shfl_xor(acc.x, m);
        acc.y += __shfl_xor(acc.y, m);
        acc.z += __shfl_xor(acc.z, m);
        acc.w += __shfl_xor(acc.w, m);
        ssum += __shfl_xor(ssum, m);
    }

    if (slot == 0) {
        float inv = 1.f / fmaxf(ssum, 1e-9f);
        float4 bv = *(const float4*)&bias[head * HID + half32 + fl];
        float r0 = acc.x * inv + bv.x;
        float r1 = acc.y * inv + bv.y;
        float r2 = acc.z * inv + bv.z;
        float r3 = acc.w * inv + bv.w;
        r0 = (r0 > 0.f) ? r0 : expm1f(r0);
        r1 = (r1 > 0.f) ? r1 : expm1f(r1);
        r2 = (r2 > 0.f) ? r2 : expm1f(r2);
        r3 = (r3 > 0.f) ? r3 : expm1f(r3);
        if (mode) {
            float4 rv = make_float4(r0, r1, r2, r3);
            *(float4*)&out[(size_t)head * N_NODES * HID + (size_t)n * HID + half32 + fl] = rv;
        } else {
            half4 hv = {(_Float16)r0, (_Float16)r1, (_Float16)r2, (_Float16)r3};
            *(half4*)&h1[(size_t)sl * SLAB + (size_t)n * 32 + fl] = hv;
        }
    }
}

// ---------------------------------------------------------------- launch

extern "C" void kernel_launch(void* const* d_in, const int* in_sizes, int n_in,
                              void* d_out, int out_size, void* d_ws, size_t ws_size,
                              hipStream_t stream) {
    const float* x   = (const float*)d_in[0];
    const int*   src = (const int*)d_in[1];
    const int*   dst = (const int*)d_in[2];
    const float* W0  = (const float*)d_in[3];
    const float* al0 = (const float*)d_in[4];
    const float* ar0 = (const float*)d_in[5];
    const float* b0  = (const float*)d_in[6];
    const float* W1  = (const float*)d_in[7];
    const float* al1 = (const float*)d_in[8];
    const float* ar1 = (const float*)d_in[9];
    const float* b1  = (const float*)d_in[10];
    float* out = (float*)d_out;

    // h1 (layer-1 hidden, fp16 slice-major, 25.6 MB) lives in d_out until the
    // final agg_fused(mode=1) overwrites d_out with the fp32 output. Sequential
    // on stream: agg(mode0) writes h1 -> gemm<1> reads h1 -> agg(mode1) writes out.
    _Float16* h1 = (_Float16*)d_out;

    // workspace layout
    _Float16* feat16 = (_Float16*)d_ws;                          // 8 slabs = N*256 fp16
    _Float16* wt0 = feat16 + (size_t)N_NODES * FDIM;             // 256*256
    _Float16* wt1 = wt0 + FDIM * FDIM;                           // 256*256
    float* el    = (float*)(wt1 + FDIM * FDIM);                  // N*4
    float* er    = el + N_NODES * HEADS;                         // N*4
    int* counts  = (int*)(er + N_NODES * HEADS);                 // N
    int* cursor  = counts + N_NODES;                             // N
    int* offs    = cursor + N_NODES;                             // N+1 (pad 50016)
    int* bsum    = offs + 50016;                                 // 64
    int* csr_src = bsum + 64;                                    // E

    // ---- prep + CSR build
    hipMemsetAsync(counts, 0, 2 * N_NODES * sizeof(int), stream);  // counts + cursor
    wcast_kernel<<<dim3(16, 2), 256, 0, stream>>>(W0, W1, wt0, wt1);
    hist_kernel<<<(N_EDGES + 255) / 256, 256, 0, stream>>>(dst, counts, N_EDGES);
    scan_local<<<SCAN_NB, 256, 0, stream>>>(counts, offs, bsum, N_NODES);
    scan_bsum<<<1, 64, 0, stream>>>(bsum, offs, SCAN_NB, N_NODES);
    scan_add<<<SCAN_NB, 256, 0, stream>>>(offs, bsum, N_NODES);
    scatter_kernel<<<(N_EDGES + 255) / 256, 256, 0, stream>>>(src, dst, offs, cursor, csr_src, N_EDGES);

    dim3 ggrid((N_NODES + 127) / 128, FDIM / 128);
    const int agg_grid = (N_NODES / 8) * 8;   // (node-groups of 8) x 8 slices

    // ---- layer 1 (A = x fp32, converted in staging; h1 written into d_out)
    mfma_gemm<0><<<ggrid, 256, 0, stream>>>(x, nullptr, wt0, al0, ar0, feat16, el, er);
    agg_fused<<<agg_grid, 512, 0, stream>>>(feat16, el, er, b0, offs, csr_src,
                                            out, h1, 0);

    // ---- layer 2 (A = h1 fp16 slice-major; final head-major fp32 write)
    mfma_gemm<1><<<ggrid, 256, 0, stream>>>(nullptr, h1, wt1, al1, ar1, feat16, el, er);
    agg_fused<<<agg_grid, 512, 0, stream>>>(feat16, el, er, b1, offs, csr_src,
                                            out, h1, 1);
}